// Round 8
// baseline (71.665 us; speedup 1.0000x reference)
//
#include <hip/hip_runtime.h>
#include <hip/hip_bf16.h>

// ============================================================================
// R8 = MEASUREMENT ROUND. Byte-identical R7 fused kernel, dispatched 3x
// back-to-back. Marginal cost per dispatch (n + T_fused) =
// (dur_R8 - dur_R7)/2 decomposes the 27.4us into harness-fixed vs kernel
// cost. Runs 2,3 are exact recomputations (counters self-reset; stream
// serialization + kernel-boundary coherence). Deterministic, same output.
// ============================================================================

// Problem constants (fixed by setup_inputs)
constexpr int B  = 32;
constexpr int H  = 640;
constexpr int Wd = 640;
constexpr int M  = 256;

// Measured-best grid (R3): 3200 blocks x 256 threads, 4 f4-iters.
constexpr int CHUNKS       = 100;                 // blocks per image
constexpr int F4_PER_IMG   = H * Wd / 4;          // 102400
constexpr int F4_PER_BLOCK = F4_PER_IMG / CHUNKS; // 1024 float4 per block
constexpr int NBLK         = B * CHUNKS;          // 3200 blocks

// Counters start at 0xAAAAAAAA (fresh poison) or 0 (restored by previous
// run's winner). Winner checks accept both; winner resets to 0.
constexpr unsigned POISON = 0xAAAAAAAAu;

// Workspace layout (bytes). Nothing memset (R6: memset node ~5us).
//   [0,4)            : unsigned gcnt
//   [4096 + i*256)   : unsigned imgcnt[i], i<32
//   [16384, +128)    : float imgsum[32]     (fully written before read)
//   [20480, +12800)  : float partials[3200] (fully written before read)
constexpr size_t WS_IMGCNT_OFF   = 4096;
constexpr size_t WS_IMGSUM_OFF   = 16384;
constexpr size_t WS_PARTIALS_OFF = 20480;

__global__ __launch_bounds__(256) void fused_bce(
    const float* __restrict__ seg_preds,
    const float* __restrict__ bboxes,
    const int* __restrict__ batch_idx,
    const unsigned char* __restrict__ is_seg,
    unsigned int* __restrict__ gcnt,
    unsigned int* __restrict__ imgcnt,     // stride 64 uints (256 B)
    float* __restrict__ imgsum,
    float* __restrict__ partials,
    float* __restrict__ out)
{
    const int img   = blockIdx.x / CHUNKS;
    const int chunk = blockIdx.x % CHUNKS;

    __shared__ ushort4 sbox[M];
    __shared__ int scount;
    __shared__ float wsum[4];
    __shared__ int sflag;
    __shared__ double sd[128];

    const int p_start = chunk * F4_PER_BLOCK * 4;
    const int row_lo  = p_start / Wd;
    const int row_hi  = (p_start + F4_PER_BLOCK * 4 - 1) / Wd;

    if (threadIdx.x == 0) scount = 0;
    __syncthreads();

    // ---- derive this image's row-overlapping boxes (bit-identical f32 math)
    if (threadIdx.x < M) {
        const float4 bb = ((const float4*)bboxes)[threadIdx.x];
        if (batch_idx[threadIdx.x] == img) {
            float cx = bb.x * 640.0f, cy = bb.y * 640.0f;
            float bw = bb.z * 640.0f, bh = bb.w * 640.0f;
            float x1f = fminf(fmaxf(cx - bw * 0.5f, 0.0f), 639.0f);
            float y1f = fminf(fmaxf(cy - bh * 0.5f, 0.0f), 639.0f);
            float x2f = fminf(fmaxf(cx + bw * 0.5f, 0.0f), 639.0f);
            float y2f = fminf(fmaxf(cy + bh * 0.5f, 0.0f), 639.0f);
            int y1 = (int)y1f, y2 = (int)y2f;
            if (y1 <= row_hi && y2 >= row_lo) {
                ushort4 bx;
                bx.x = (unsigned short)(int)x1f;
                bx.y = (unsigned short)y1;
                bx.z = (unsigned short)(int)x2f;
                bx.w = (unsigned short)y2;
                int slot = atomicAdd(&scount, 1);  // LDS; order-independent union
                sbox[slot] = bx;
            }
        }
    }
    __syncthreads();
    const int  ncnt = scount;
    const bool det  = (is_seg[img] == 0);

    const float4* __restrict__ xin =
        (const float4*)(seg_preds + (size_t)img * H * Wd);

    // ---- streaming BCE partial (identical per-pixel math: absmax 0.0)
    float acc = 0.0f;
    #pragma unroll
    for (int k = 0; k < 4; ++k) {
        const int    f4 = chunk * F4_PER_BLOCK + k * 256 + threadIdx.x;
        const float4 v  = xin[f4];
        const int p   = f4 * 4;
        const int row = p / Wd;
        const int col = p - row * Wd;

        unsigned covm = 0u;
        if (det) {
            for (int i = 0; i < ncnt; ++i) {
                ushort4 bx = sbox[i];
                if (row >= (int)bx.y && row <= (int)bx.w) {
                    int lo = max((int)bx.x - col, 0);
                    int hi = min((int)bx.z - col, 3);
                    if (lo <= hi) covm |= ((1u << (hi - lo + 1)) - 1u) << lo;
                    if (covm == 0xFu) break;
                }
            }
        }
        const float vals[4] = {v.x, v.y, v.z, v.w};
        #pragma unroll
        for (int j = 0; j < 4; ++j) {
            float xv = vals[j];
            float a  = fabsf(xv);
            float sp = __logf(1.0f + __expf(-a));
            float term = fmaxf(xv, 0.0f) + sp;
            if (covm & (1u << j)) term -= xv;
            acc += term;
        }
    }

    // ---- block reduce
    for (int off = 32; off > 0; off >>= 1)
        acc += __shfl_down(acc, off, 64);
    const int lane = threadIdx.x & 63;
    const int wid  = threadIdx.x >> 6;
    if (lane == 0) wsum[wid] = acc;
    __syncthreads();

    // ---- publish partial, bump per-image counter
    if (threadIdx.x == 0) {
        float p = wsum[0] + wsum[1] + wsum[2] + wsum[3];
        float oldp = atomicExch(&partials[blockIdx.x], p);
        __asm__ volatile("" : : "v"(oldp));
        __builtin_amdgcn_s_waitcnt(0);
        __builtin_amdgcn_sched_barrier(0);
        unsigned old = atomicAdd(&imgcnt[img * 64], 1u);
        int win = (old == (unsigned)(CHUNKS - 1)) ||
                  (old == POISON + (unsigned)(CHUNKS - 1));
        if (win) atomicExch(&imgcnt[img * 64], 0u);
        sflag = win;
    }
    __syncthreads();
    if (!sflag) return;

    // ---- image finalizer: fixed-order f64 sum of 100 partials
    {
        const int t = threadIdx.x;
        double v = 0.0;
        if (t < CHUNKS)
            v = (double)atomicAdd(&partials[img * CHUNKS + t], 0.0f);
        if (t < 128) sd[t] = v;
        __syncthreads();
        for (int off = 64; off > 0; off >>= 1) {
            if (t < off) sd[t] += sd[t + off];
            __syncthreads();
        }
        if (t == 0) {
            float oldv = atomicExch(&imgsum[img], (float)sd[0]);
            __asm__ volatile("" : : "v"(oldv));
            __builtin_amdgcn_s_waitcnt(0);
            __builtin_amdgcn_sched_barrier(0);
            unsigned old2 = atomicAdd(gcnt, 1u);
            int win2 = (old2 == (unsigned)(B - 1)) ||
                       (old2 == POISON + (unsigned)(B - 1));
            if (win2) atomicExch(gcnt, 0u);
            sflag = win2 ? 2 : 0;
        }
        __syncthreads();
    }
    if (sflag != 2) return;

    // ---- global finalizer: fixed-order f64 tree -> out
    {
        const int t = threadIdx.x;
        double v = 0.0;
        if (t < B) v = (double)atomicAdd(&imgsum[t], 0.0f);
        if (t < 64) sd[t] = v;
        __syncthreads();
        for (int off = 32; off > 0; off >>= 1) {
            if (t < off) sd[t] += sd[t + off];
            __syncthreads();
        }
        if (t == 0) {
            int nd = 0;
            for (int b = 0; b < B; ++b) nd += (is_seg[b] == 0) ? 1 : 0;
            double hd   = (nd > 0) ? 1.0 : 0.0;
            double mean = sd[0] / (double)((size_t)B * H * Wd);
            out[0] = (float)(0.1 * mean * hd);
        }
    }
}

extern "C" void kernel_launch(void* const* d_in, const int* in_sizes, int n_in,
                              void* d_out, int out_size, void* d_ws, size_t ws_size,
                              hipStream_t stream)
{
    const float*         seg_preds = (const float*)d_in[0];
    const float*         bboxes    = (const float*)d_in[1];
    const int*           batch_idx = (const int*)d_in[2];
    const unsigned char* is_seg    = (const unsigned char*)d_in[3];

    unsigned int* gcnt     = (unsigned int*)d_ws;
    unsigned int* imgcnt   = (unsigned int*)((char*)d_ws + WS_IMGCNT_OFF);
    float*        imgsum   = (float*)((char*)d_ws + WS_IMGSUM_OFF);
    float*        partials = (float*)((char*)d_ws + WS_PARTIALS_OFF);
    float*        out      = (float*)d_out;

    // MEASUREMENT: 3 identical dispatches. Marginal cost per dispatch
    // = (dur - 27.4)/2. Runs 2,3 recompute the same output (counters are
    // winner-reset to 0 before each kernel retires; stream-serialized).
    fused_bce<<<NBLK, 256, 0, stream>>>(seg_preds, bboxes, batch_idx, is_seg,
                                        gcnt, imgcnt, imgsum, partials, out);
    fused_bce<<<NBLK, 256, 0, stream>>>(seg_preds, bboxes, batch_idx, is_seg,
                                        gcnt, imgcnt, imgsum, partials, out);
    fused_bce<<<NBLK, 256, 0, stream>>>(seg_preds, bboxes, batch_idx, is_seg,
                                        gcnt, imgcnt, imgsum, partials, out);
}

// Round 9
// 25.236 us; speedup vs baseline: 2.8398x; 2.8398x over previous
//
#include <hip/hip_runtime.h>
#include <hip/hip_bf16.h>

// Problem constants (fixed by setup_inputs)
constexpr int B  = 32;
constexpr int H  = 640;
constexpr int Wd = 640;
constexpr int M  = 256;

// Measured-best grid (R3): 3200 blocks x 256 threads, 4 f4-iters.
constexpr int CHUNKS       = 100;                 // blocks per image
constexpr int F4_PER_IMG   = H * Wd / 4;          // 102400
constexpr int F4_PER_BLOCK = F4_PER_IMG / CHUNKS; // 1024 float4 per block
constexpr int NBLK         = B * CHUNKS;          // 3200 blocks

// --------------------------------------------------------------------------
// Deterministic single-RMW tail (R8 measurement: old tail cost ~8us).
// Each u64 accumulator packs {count : bits 52+, value : bits 0..51}.
// Integer atomicAdd is associative -> bit-deterministic in any order.
// Bounds: block partial <= 4096*6.7 ~ 2^14.8; x2^20 scale ~ 2^34.8.
//   image sum  <= 2^41.5  < 2^52 (no carry into count field)
//   global sum <  2^46.5  < 2^52
// Poison start: low52(0xAA..) ~ 0.67*2^52; headroom 0.33*2^52 ~ 2^50.4 >> sums.
// Winner checks accept both start bases {0, POISON}; winner resets to 0,
// restoring the invariant for subsequent graph replays (R5/R6 lessons).
// --------------------------------------------------------------------------
constexpr unsigned long long COUNT_UNIT = 1ull << 52;
constexpr unsigned long long VAL_MASK   = COUNT_UNIT - 1ull;
constexpr unsigned long long POISON64   = 0xAAAAAAAAAAAAAAAAull;
constexpr unsigned long long POISON_HI  = POISON64 >> 52;      // 0xAAA

// Workspace layout (bytes). Nothing memset (R6: a memset node costs ~5us).
//   [0,8)           : u64 gacc
//   [4096 + i*256)  : u64 imgacc[i], i<32  (256B stride: no line sharing)
constexpr size_t WS_IMGACC_OFF = 4096;

__global__ __launch_bounds__(256) void fused_bce(
    const float* __restrict__ seg_preds,
    const float* __restrict__ bboxes,
    const int* __restrict__ batch_idx,
    const unsigned char* __restrict__ is_seg,
    unsigned long long* __restrict__ gacc,
    unsigned long long* __restrict__ imgacc,   // stride 32 u64 (256 B)
    float* __restrict__ out)
{
    const int img   = blockIdx.x / CHUNKS;
    const int chunk = blockIdx.x % CHUNKS;

    __shared__ ushort4 sbox[M];
    __shared__ int scount;
    __shared__ float wsum[4];

    // pixel range of this block -> row range
    const int p_start = chunk * F4_PER_BLOCK * 4;
    const int row_lo  = p_start / Wd;
    const int row_hi  = (p_start + F4_PER_BLOCK * 4 - 1) / Wd;

    if (threadIdx.x == 0) scount = 0;
    __syncthreads();

    // ---- derive this image's row-overlapping boxes (bit-identical f32 math)
    if (threadIdx.x < M) {
        const float4 bb = ((const float4*)bboxes)[threadIdx.x];
        if (batch_idx[threadIdx.x] == img) {
            float cx = bb.x * 640.0f, cy = bb.y * 640.0f;
            float bw = bb.z * 640.0f, bh = bb.w * 640.0f;
            float x1f = fminf(fmaxf(cx - bw * 0.5f, 0.0f), 639.0f);
            float y1f = fminf(fmaxf(cy - bh * 0.5f, 0.0f), 639.0f);
            float x2f = fminf(fmaxf(cx + bw * 0.5f, 0.0f), 639.0f);
            float y2f = fminf(fmaxf(cy + bh * 0.5f, 0.0f), 639.0f);
            int y1 = (int)y1f, y2 = (int)y2f;
            if (y1 <= row_hi && y2 >= row_lo) {
                ushort4 bx;
                bx.x = (unsigned short)(int)x1f;
                bx.y = (unsigned short)y1;
                bx.z = (unsigned short)(int)x2f;
                bx.w = (unsigned short)y2;
                int slot = atomicAdd(&scount, 1);  // LDS; order-independent union
                sbox[slot] = bx;
            }
        }
    }
    __syncthreads();
    const int  ncnt = scount;
    const bool det  = (is_seg[img] == 0);

    const float4* __restrict__ xin =
        (const float4*)(seg_preds + (size_t)img * H * Wd);

    // ---- streaming BCE partial (identical per-pixel math since R1)
    float acc = 0.0f;
    #pragma unroll
    for (int k = 0; k < 4; ++k) {
        const int    f4 = chunk * F4_PER_BLOCK + k * 256 + threadIdx.x;
        const float4 v  = xin[f4];
        const int p   = f4 * 4;
        const int row = p / Wd;
        const int col = p - row * Wd;

        unsigned covm = 0u;
        if (det) {
            for (int i = 0; i < ncnt; ++i) {
                ushort4 bx = sbox[i];
                if (row >= (int)bx.y && row <= (int)bx.w) {
                    int lo = max((int)bx.x - col, 0);
                    int hi = min((int)bx.z - col, 3);
                    if (lo <= hi) covm |= ((1u << (hi - lo + 1)) - 1u) << lo;
                    if (covm == 0xFu) break;
                }
            }
        }
        const float vals[4] = {v.x, v.y, v.z, v.w};
        #pragma unroll
        for (int j = 0; j < 4; ++j) {
            float xv = vals[j];
            float a  = fabsf(xv);
            float sp = __logf(1.0f + __expf(-a));
            float term = fmaxf(xv, 0.0f) + sp;
            if (covm & (1u << j)) term -= xv;
            acc += term;
        }
    }

    // ---- block reduce (wave64 shuffle, then 4 waves)
    for (int off = 32; off > 0; off >>= 1)
        acc += __shfl_down(acc, off, 64);
    const int lane = threadIdx.x & 63;
    const int wid  = threadIdx.x >> 6;
    if (lane == 0) wsum[wid] = acc;
    __syncthreads();

    // ---- tail: ONE u64 RMW per block; winners chain upward. Thread 0 only.
    if (threadIdx.x == 0) {
        float p = wsum[0] + wsum[1] + wsum[2] + wsum[3];   // p > 0 always
        // exact f64 quantization at 2^20 (block partial < 2^15)
        unsigned long long my =
            (unsigned long long)((double)p * 1048576.0 + 0.5) + COUNT_UNIT;
        unsigned long long old = atomicAdd(&imgacc[img * 32], my);
        unsigned long long cnt = old >> 52;
        if (cnt == (unsigned long long)(CHUNKS - 1) ||
            cnt == POISON_HI + (unsigned long long)(CHUNKS - 1)) {
            // image winner: old's low bits are the other 99 partials' sum
            unsigned long long base =
                (cnt == (unsigned long long)(CHUNKS - 1)) ? 0ull : POISON64;
            unsigned long long img_total =
                ((old - base) & VAL_MASK) + (my & VAL_MASK);
            atomicExch(&imgacc[img * 32], 0ull);           // restore invariant
            unsigned long long g_old = atomicAdd(gacc, img_total + COUNT_UNIT);
            unsigned long long gc = g_old >> 52;
            if (gc == (unsigned long long)(B - 1) ||
                gc == POISON_HI + (unsigned long long)(B - 1)) {
                // global winner: compute final scalar
                unsigned long long gbase =
                    (gc == (unsigned long long)(B - 1)) ? 0ull : POISON64;
                unsigned long long total =
                    ((g_old - gbase) & VAL_MASK) + img_total;
                atomicExch(gacc, 0ull);                    // restore invariant
                int nd = 0;
                for (int b = 0; b < B; ++b) nd += (is_seg[b] == 0) ? 1 : 0;
                double hd   = (nd > 0) ? 1.0 : 0.0;
                double mean = ((double)total * (1.0 / 1048576.0))
                              / (double)((size_t)B * H * Wd);
                out[0] = (float)(0.1 * mean * hd);
            }
        }
    }
}

extern "C" void kernel_launch(void* const* d_in, const int* in_sizes, int n_in,
                              void* d_out, int out_size, void* d_ws, size_t ws_size,
                              hipStream_t stream)
{
    const float*         seg_preds = (const float*)d_in[0];
    const float*         bboxes    = (const float*)d_in[1];
    const int*           batch_idx = (const int*)d_in[2];
    const unsigned char* is_seg    = (const unsigned char*)d_in[3];

    unsigned long long* gacc   = (unsigned long long*)d_ws;
    unsigned long long* imgacc = (unsigned long long*)((char*)d_ws + WS_IMGACC_OFF);
    float*              out    = (float*)d_out;

    // Single graph node; no memset (poison-aware self-resetting accumulators).
    fused_bce<<<NBLK, 256, 0, stream>>>(seg_preds, bboxes, batch_idx, is_seg,
                                        gacc, imgacc, out);
}

// Round 10
// 20.621 us; speedup vs baseline: 3.4753x; 1.2238x over previous
//
#include <hip/hip_runtime.h>
#include <hip/hip_bf16.h>

// Problem constants (fixed by setup_inputs)
constexpr int B  = 32;
constexpr int H  = 640;
constexpr int Wd = 640;
constexpr int M  = 256;

// Measured-best grid (R3): 3200 blocks x 256 threads, 4 f4-iters.
constexpr int CHUNKS       = 100;                 // blocks per image
constexpr int F4_PER_IMG   = H * Wd / 4;          // 102400
constexpr int F4_PER_BLOCK = F4_PER_IMG / CHUNKS; // 1024 float4 (4096 px)
constexpr int NBLK         = B * CHUNKS;          // 3200 blocks

constexpr int NROWS_MAX = 8;    // 4096 px span <= 8 rows of 640
constexpr int WPR       = 20;   // 640 cols / 32 bits

// Deterministic single-RMW tail (R9: passed, absmax 0.0, -2.2us).
// u64 packs {count : bits 52+, value : bits 0..51}; integer add is
// associative -> order-independent. Poison-aware (start in {0, 0xAA..}),
// winners reset to 0 (R5/R6 lessons). Bounds: image sum < 2^42, global
// sum < 2^47, poison low-52 headroom ~2^50 — no carry into count field.
constexpr unsigned long long COUNT_UNIT = 1ull << 52;
constexpr unsigned long long VAL_MASK   = COUNT_UNIT - 1ull;
constexpr unsigned long long POISON64   = 0xAAAAAAAAAAAAAAAAull;
constexpr unsigned long long POISON_HI  = POISON64 >> 52;      // 0xAAA

// Workspace layout (bytes). Nothing memset (R6: a memset node costs ~5us).
//   [0,8)           : u64 gacc
//   [4096 + i*256)  : u64 imgacc[i], i<32  (256B stride: no line sharing)
constexpr size_t WS_IMGACC_OFF = 4096;

__global__ __launch_bounds__(256) void fused_bce(
    const float* __restrict__ seg_preds,
    const float* __restrict__ bboxes,
    const int* __restrict__ batch_idx,
    const unsigned char* __restrict__ is_seg,
    unsigned long long* __restrict__ gacc,
    unsigned long long* __restrict__ imgacc,   // stride 32 u64 (256 B)
    float* __restrict__ out)
{
    const int img   = blockIdx.x / CHUNKS;
    const int chunk = blockIdx.x % CHUNKS;

    __shared__ ushort4 sbox[M];
    __shared__ int scount;
    __shared__ unsigned sbm[NROWS_MAX * WPR];   // column coverage bitmaps
    __shared__ float wsum[4];

    // pixel range of this block -> row range (<= 8 rows)
    const int p_start = chunk * F4_PER_BLOCK * 4;
    const int row_lo  = p_start / Wd;
    const int row_hi  = (p_start + F4_PER_BLOCK * 4 - 1) / Wd;
    const int nrows   = row_hi - row_lo + 1;

    const bool det = (is_seg[img] == 0);

    if (threadIdx.x == 0) scount = 0;
    __syncthreads();

    // ---- gather this image's row-overlapping boxes (bit-identical f32 math)
    if (threadIdx.x < M && det) {
        const float4 bb = ((const float4*)bboxes)[threadIdx.x];
        if (batch_idx[threadIdx.x] == img) {
            float cx = bb.x * 640.0f, cy = bb.y * 640.0f;
            float bw = bb.z * 640.0f, bh = bb.w * 640.0f;
            float x1f = fminf(fmaxf(cx - bw * 0.5f, 0.0f), 639.0f);
            float y1f = fminf(fmaxf(cy - bh * 0.5f, 0.0f), 639.0f);
            float x2f = fminf(fmaxf(cx + bw * 0.5f, 0.0f), 639.0f);
            float y2f = fminf(fmaxf(cy + bh * 0.5f, 0.0f), 639.0f);
            int y1 = (int)y1f, y2 = (int)y2f;
            if (y1 <= row_hi && y2 >= row_lo) {
                ushort4 bx;
                bx.x = (unsigned short)(int)x1f;
                bx.y = (unsigned short)y1;
                bx.z = (unsigned short)(int)x2f;
                bx.w = (unsigned short)y2;
                int slot = atomicAdd(&scount, 1);  // LDS; order-independent union
                sbox[slot] = bx;
            }
        }
    }
    __syncthreads();
    const int ncnt = scount;

    // ---- build per-row column bitmaps (one pass; 140-160 (row,word) pairs)
    for (int i = threadIdx.x; i < nrows * WPR; i += 256) {
        const int r    = row_lo + i / WPR;
        const int w32  = (i % WPR) << 5;        // first column of this word
        unsigned m = 0u;
        for (int bi = 0; bi < ncnt; ++bi) {
            ushort4 bx = sbox[bi];
            if (r >= (int)bx.y && r <= (int)bx.w) {
                int lo = max((int)bx.x - w32, 0);
                int hi = min((int)bx.z - w32, 31);
                if (lo <= hi)
                    m |= (0xFFFFFFFFu >> (31 - hi)) & (0xFFFFFFFFu << lo);
            }
        }
        sbm[i] = m;
    }
    __syncthreads();

    const float4* __restrict__ xin =
        (const float4*)(seg_preds + (size_t)img * H * Wd);

    // ---- streaming BCE: coverage = 1 LDS word read per float4 (was ~40 VALU)
    float accA = 0.0f;   // sum of max(x,0) + softplus  (coverage-independent)
    float accB = 0.0f;   // sum of covered x            (subtract at the end)
    #pragma unroll
    for (int k = 0; k < 4; ++k) {
        const int    f4 = chunk * F4_PER_BLOCK + k * 256 + threadIdx.x;
        const float4 v  = xin[f4];
        const int p    = f4 * 4;
        const int row  = p / Wd;
        const int col  = p - row * Wd;
        const unsigned word = sbm[(row - row_lo) * WPR + (col >> 5)];
        const unsigned cov4 = (word >> (col & 31)) & 0xFu;

        const float vals[4] = {v.x, v.y, v.z, v.w};
        #pragma unroll
        for (int j = 0; j < 4; ++j) {
            float xv = vals[j];
            float a  = fabsf(xv);
            float sp = __logf(1.0f + __expf(-a));     // same math as R1-R9
            accA += fmaxf(xv, 0.0f) + sp;
            accB += (cov4 & (1u << j)) ? xv : 0.0f;   // cndmask + add
        }
    }
    float acc = accA - accB;   // per-pixel terms all >= 0 -> partial >= 0

    // ---- block reduce (wave64 shuffle, then 4 waves)
    for (int off = 32; off > 0; off >>= 1)
        acc += __shfl_down(acc, off, 64);
    const int lane = threadIdx.x & 63;
    const int wid  = threadIdx.x >> 6;
    if (lane == 0) wsum[wid] = acc;
    __syncthreads();

    // ---- tail: ONE u64 RMW per block; winners chain upward (R9, unchanged)
    if (threadIdx.x == 0) {
        float p = wsum[0] + wsum[1] + wsum[2] + wsum[3];
        unsigned long long my =
            (unsigned long long)((double)p * 1048576.0 + 0.5) + COUNT_UNIT;
        unsigned long long old = atomicAdd(&imgacc[img * 32], my);
        unsigned long long cnt = old >> 52;
        if (cnt == (unsigned long long)(CHUNKS - 1) ||
            cnt == POISON_HI + (unsigned long long)(CHUNKS - 1)) {
            unsigned long long base =
                (cnt == (unsigned long long)(CHUNKS - 1)) ? 0ull : POISON64;
            unsigned long long img_total =
                ((old - base) & VAL_MASK) + (my & VAL_MASK);
            atomicExch(&imgacc[img * 32], 0ull);           // restore invariant
            unsigned long long g_old = atomicAdd(gacc, img_total + COUNT_UNIT);
            unsigned long long gc = g_old >> 52;
            if (gc == (unsigned long long)(B - 1) ||
                gc == POISON_HI + (unsigned long long)(B - 1)) {
                unsigned long long gbase =
                    (gc == (unsigned long long)(B - 1)) ? 0ull : POISON64;
                unsigned long long total =
                    ((g_old - gbase) & VAL_MASK) + img_total;
                atomicExch(gacc, 0ull);                    // restore invariant
                int nd = 0;
                for (int b = 0; b < B; ++b) nd += (is_seg[b] == 0) ? 1 : 0;
                double hd   = (nd > 0) ? 1.0 : 0.0;
                double mean = ((double)total * (1.0 / 1048576.0))
                              / (double)((size_t)B * H * Wd);
                out[0] = (float)(0.1 * mean * hd);
            }
        }
    }
}

extern "C" void kernel_launch(void* const* d_in, const int* in_sizes, int n_in,
                              void* d_out, int out_size, void* d_ws, size_t ws_size,
                              hipStream_t stream)
{
    const float*         seg_preds = (const float*)d_in[0];
    const float*         bboxes    = (const float*)d_in[1];
    const int*           batch_idx = (const int*)d_in[2];
    const unsigned char* is_seg    = (const unsigned char*)d_in[3];

    unsigned long long* gacc   = (unsigned long long*)d_ws;
    unsigned long long* imgacc = (unsigned long long*)((char*)d_ws + WS_IMGACC_OFF);
    float*              out    = (float*)d_out;

    // Single graph node; no memset (poison-aware self-resetting accumulators).
    fused_bce<<<NBLK, 256, 0, stream>>>(seg_preds, bboxes, batch_idx, is_seg,
                                        gacc, imgacc, out);
}